// Round 2
// baseline (123.212 us; speedup 1.0000x reference)
//
#include <hip/hip_runtime.h>

#define NVOX 200000

// ---------------- K1: compact rulebook + histogram + conv0 (C=4 -> D=16) ----------------
__global__ __launch_bounds__(256) void k1_compact_conv0(
    const float* __restrict__ feats,  // [N,4]
    const int* __restrict__ nbr,      // [N,27]
    const float* __restrict__ W,      // [27,4,16]
    const float* __restrict__ s, const float* __restrict__ b,
    int* __restrict__ ent,            // [27,N] packed (idx<<5)|k
    int* __restrict__ cnt,            // [N]
    int* __restrict__ hist,           // [28]
    float* __restrict__ x) {          // [N,16]
    __shared__ float Wl[27 * 68];     // 64-float blocks padded to 68 (quad-bank spread)
    __shared__ int lhist[28];
    int t = threadIdx.x;
    for (int i = t; i < 27 * 64; i += 256)
        Wl[(i >> 6) * 68 + (i & 63)] = W[i];
    if (t < 28) lhist[t] = 0;
    __syncthreads();

    int n = blockIdx.x * 256 + t;
    if (n < NVOX) {
        float acc[16];
        #pragma unroll
        for (int d = 0; d < 16; ++d) acc[d] = 0.f;
        int c = 0;
        #pragma unroll
        for (int k = 0; k < 27; ++k) {
            int idx = nbr[n * 27 + k];
            if (idx >= 0) {
                ent[c * NVOX + n] = (idx << 5) | k;
                ++c;
                float4 f = *(const float4*)(feats + idx * 4);
                float g[4] = {f.x, f.y, f.z, f.w};
                const float4* wrow = (const float4*)(Wl + k * 68);
                #pragma unroll
                for (int cc = 0; cc < 4; ++cc) {
                    float gc = g[cc];
                    float4 w0 = wrow[cc * 4 + 0];
                    float4 w1 = wrow[cc * 4 + 1];
                    float4 w2 = wrow[cc * 4 + 2];
                    float4 w3 = wrow[cc * 4 + 3];
                    acc[0]  += gc * w0.x; acc[1]  += gc * w0.y; acc[2]  += gc * w0.z; acc[3]  += gc * w0.w;
                    acc[4]  += gc * w1.x; acc[5]  += gc * w1.y; acc[6]  += gc * w1.z; acc[7]  += gc * w1.w;
                    acc[8]  += gc * w2.x; acc[9]  += gc * w2.y; acc[10] += gc * w2.z; acc[11] += gc * w2.w;
                    acc[12] += gc * w3.x; acc[13] += gc * w3.y; acc[14] += gc * w3.z; acc[15] += gc * w3.w;
                }
            }
        }
        cnt[n] = c;
        atomicAdd(&lhist[c], 1);
        float4* o = (float4*)(x + n * 16);
        #pragma unroll
        for (int q = 0; q < 4; ++q) {
            float4 r;
            float v0 = acc[q * 4 + 0] * s[q * 4 + 0] + b[q * 4 + 0];
            float v1 = acc[q * 4 + 1] * s[q * 4 + 1] + b[q * 4 + 1];
            float v2 = acc[q * 4 + 2] * s[q * 4 + 2] + b[q * 4 + 2];
            float v3 = acc[q * 4 + 3] * s[q * 4 + 3] + b[q * 4 + 3];
            r.x = v0 > 0.f ? v0 : 0.f;
            r.y = v1 > 0.f ? v1 : 0.f;
            r.z = v2 > 0.f ? v2 : 0.f;
            r.w = v3 > 0.f ? v3 : 0.f;
            o[q] = r;
        }
    }
    __syncthreads();
    if (t < 28 && lhist[t]) atomicAdd(&hist[t], lhist[t]);
}

// ---------------- K2: 28-bin exclusive scan -> cursor ----------------
__global__ void k2_scan(const int* __restrict__ hist, int* __restrict__ cursor) {
    if (threadIdx.x == 0 && blockIdx.x == 0) {
        int acc = 0;
        for (int c = 0; c < 28; ++c) {
            cursor[c] = acc;
            acc += hist[c];
        }
    }
}

// ---------------- K3: counting-sort scatter; re-layout ent/cnt into sorted columns ----------------
__global__ __launch_bounds__(256) void k3_scatter(
    const int* __restrict__ ent, const int* __restrict__ cnt,
    int* __restrict__ cursor,
    int* __restrict__ entS, int* __restrict__ cntS, int* __restrict__ perm) {
    __shared__ int lcnt[28];
    __shared__ int lbase[28];
    int t = threadIdx.x;
    if (t < 28) lcnt[t] = 0;
    __syncthreads();
    int n = blockIdx.x * 256 + t;
    int c = 0, r = 0;
    if (n < NVOX) {
        c = cnt[n];
        r = atomicAdd(&lcnt[c], 1);
    }
    __syncthreads();
    if (t < 28) lbase[t] = lcnt[t] ? atomicAdd(&cursor[t], lcnt[t]) : 0;
    __syncthreads();
    if (n < NVOX) {
        int p = lbase[c] + r;
        perm[p] = n;
        cntS[p] = c;
        for (int j = 0; j < c; ++j)
            entS[j * NVOX + p] = ent[j * NVOX + n];
    }
}

// ---------------- generic 16->16 conv body over sorted column p ----------------
__device__ __forceinline__ void conv16_accum(const float* __restrict__ fin,
                                             const int* __restrict__ entS,
                                             int c, int p, const float* Wl,
                                             float acc[16]) {
    for (int j = 0; j < c; ++j) {
        int e = entS[j * NVOX + p];
        int k = e & 31;
        int idx = e >> 5;
        const float4* fp = (const float4*)(fin + idx * 16);
        float4 f0 = fp[0], f1 = fp[1], f2 = fp[2], f3 = fp[3];
        float g[16] = {f0.x, f0.y, f0.z, f0.w, f1.x, f1.y, f1.z, f1.w,
                       f2.x, f2.y, f2.z, f2.w, f3.x, f3.y, f3.z, f3.w};
        const float4* wrow = (const float4*)(Wl + k * 260);
        #pragma unroll
        for (int cc = 0; cc < 16; ++cc) {
            float gc = g[cc];
            float4 w0 = wrow[cc * 4 + 0];
            float4 w1 = wrow[cc * 4 + 1];
            float4 w2 = wrow[cc * 4 + 2];
            float4 w3 = wrow[cc * 4 + 3];
            acc[0]  += gc * w0.x; acc[1]  += gc * w0.y; acc[2]  += gc * w0.z; acc[3]  += gc * w0.w;
            acc[4]  += gc * w1.x; acc[5]  += gc * w1.y; acc[6]  += gc * w1.z; acc[7]  += gc * w1.w;
            acc[8]  += gc * w2.x; acc[9]  += gc * w2.y; acc[10] += gc * w2.z; acc[11] += gc * w2.w;
            acc[12] += gc * w3.x; acc[13] += gc * w3.y; acc[14] += gc * w3.z; acc[15] += gc * w3.w;
        }
    }
}

// ---------------- K4: conv1 (16->16), relu(conv*s+b), sorted order ----------------
__global__ __launch_bounds__(256) void k4_conv1(
    const float* __restrict__ fin,    // x [N,16] original order
    const int* __restrict__ entS, const int* __restrict__ cntS,
    const int* __restrict__ perm,
    const float* __restrict__ W,      // [27,16,16]
    const float* __restrict__ s, const float* __restrict__ b,
    float* __restrict__ out) {        // h [N,16] original order
    __shared__ float Wl[27 * 260];
    for (int i = threadIdx.x; i < 27 * 256; i += 256)
        Wl[(i >> 8) * 260 + (i & 255)] = W[i];
    __syncthreads();
    int p = blockIdx.x * 256 + threadIdx.x;
    if (p >= NVOX) return;
    int n = perm[p];
    int c = cntS[p];
    float acc[16];
    #pragma unroll
    for (int d = 0; d < 16; ++d) acc[d] = 0.f;
    conv16_accum(fin, entS, c, p, Wl, acc);
    float4* o = (float4*)(out + n * 16);
    #pragma unroll
    for (int q = 0; q < 4; ++q) {
        float4 r;
        float v0 = acc[q * 4 + 0] * s[q * 4 + 0] + b[q * 4 + 0];
        float v1 = acc[q * 4 + 1] * s[q * 4 + 1] + b[q * 4 + 1];
        float v2 = acc[q * 4 + 2] * s[q * 4 + 2] + b[q * 4 + 2];
        float v3 = acc[q * 4 + 3] * s[q * 4 + 3] + b[q * 4 + 3];
        r.x = v0 > 0.f ? v0 : 0.f;
        r.y = v1 > 0.f ? v1 : 0.f;
        r.z = v2 > 0.f ? v2 : 0.f;
        r.w = v3 > 0.f ? v3 : 0.f;
        o[q] = r;
    }
}

// ---------------- K5: conv2 + residual + relu + final 16->3 linear, sorted order ----------------
__global__ __launch_bounds__(256) void k5_conv2_final(
    const float* __restrict__ fin,    // h [N,16]
    const int* __restrict__ entS, const int* __restrict__ cntS,
    const int* __restrict__ perm,
    const float* __restrict__ W,      // [27,16,16]
    const float* __restrict__ s, const float* __restrict__ b,
    const float* __restrict__ idn,    // x [N,16]
    const float* __restrict__ Wlin,   // [16,3]
    const float* __restrict__ blin,   // [3]
    float* __restrict__ out) {        // [N,3]
    __shared__ float Wl[27 * 260];
    for (int i = threadIdx.x; i < 27 * 256; i += 256)
        Wl[(i >> 8) * 260 + (i & 255)] = W[i];
    __syncthreads();
    int p = blockIdx.x * 256 + threadIdx.x;
    if (p >= NVOX) return;
    int n = perm[p];
    int c = cntS[p];
    float acc[16];
    #pragma unroll
    for (int d = 0; d < 16; ++d) acc[d] = 0.f;
    conv16_accum(fin, entS, c, p, Wl, acc);
    const float4* ip = (const float4*)(idn + n * 16);
    float4 i0 = ip[0], i1 = ip[1], i2 = ip[2], i3 = ip[3];
    float id[16] = {i0.x, i0.y, i0.z, i0.w, i1.x, i1.y, i1.z, i1.w,
                    i2.x, i2.y, i2.z, i2.w, i3.x, i3.y, i3.z, i3.w};
    float o0 = blin[0], o1 = blin[1], o2 = blin[2];
    #pragma unroll
    for (int d = 0; d < 16; ++d) {
        float v = acc[d] * s[d] + b[d] + id[d];
        v = v > 0.f ? v : 0.f;
        o0 += v * Wlin[d * 3 + 0];
        o1 += v * Wlin[d * 3 + 1];
        o2 += v * Wlin[d * 3 + 2];
    }
    out[n * 3 + 0] = o0;
    out[n * 3 + 1] = o1;
    out[n * 3 + 2] = o2;
}

extern "C" void kernel_launch(void* const* d_in, const int* in_sizes, int n_in,
                              void* d_out, int out_size, void* d_ws, size_t ws_size,
                              hipStream_t stream) {
    const float* feats = (const float*)d_in[0];
    const int*   nbr   = (const int*)d_in[1];
    const float* W0    = (const float*)d_in[2];
    const float* s0    = (const float*)d_in[3];
    const float* b0    = (const float*)d_in[4];
    const float* W1    = (const float*)d_in[5];
    const float* s1    = (const float*)d_in[6];
    const float* b1    = (const float*)d_in[7];
    const float* W2    = (const float*)d_in[8];
    const float* s2    = (const float*)d_in[9];
    const float* b2    = (const float*)d_in[10];
    const float* Wlin  = (const float*)d_in[11];
    const float* blin  = (const float*)d_in[12];
    float* out = (float*)d_out;

    char* ws = (char*)d_ws;
    int*   ent    = (int*)(ws);                  // 27*N*4 = 21,600,000
    int*   entS   = (int*)(ws + 21600000);       // 21,600,000
    int*   cnt    = (int*)(ws + 43200000);       // 800,000
    int*   cntS   = (int*)(ws + 44000000);       // 800,000
    int*   perm   = (int*)(ws + 44800000);       // 800,000
    float* x      = (float*)(ws + 45600000);     // 12,800,000
    float* h      = (float*)(ws + 58400000);     // 12,800,000
    int*   hist   = (int*)(ws + 71200000);       // 112
    int*   cursor = (int*)(ws + 71200128);       // 112

    hipMemsetAsync(hist, 0, 28 * sizeof(int), stream);

    int blocks = (NVOX + 255) / 256;
    k1_compact_conv0<<<blocks, 256, 0, stream>>>(feats, nbr, W0, s0, b0, ent, cnt, hist, x);
    k2_scan<<<1, 64, 0, stream>>>(hist, cursor);
    k3_scatter<<<blocks, 256, 0, stream>>>(ent, cnt, cursor, entS, cntS, perm);
    k4_conv1<<<blocks, 256, 0, stream>>>(x, entS, cntS, perm, W1, s1, b1, h);
    k5_conv2_final<<<blocks, 256, 0, stream>>>(h, entS, cntS, perm, W2, s2, b2, x, Wlin, blin, out);
}

// Round 3
// 67.658 us; speedup vs baseline: 1.8211x; 1.8211x over previous
//
#include <hip/hip_runtime.h>

#define NVOX 200000

// ---------------- 16x16 FMA micro-kernel: acc[16] += g[16] @ W(16x16) from LDS ----------------
__device__ __forceinline__ void fma16x16(const float4* __restrict__ wrow,
                                         float4 f0, float4 f1, float4 f2, float4 f3,
                                         float acc[16]) {
    const float g[16] = {f0.x, f0.y, f0.z, f0.w, f1.x, f1.y, f1.z, f1.w,
                         f2.x, f2.y, f2.z, f2.w, f3.x, f3.y, f3.z, f3.w};
    #pragma unroll
    for (int cc = 0; cc < 16; ++cc) {
        float gc = g[cc];
        float4 w0 = wrow[cc * 4 + 0];
        float4 w1 = wrow[cc * 4 + 1];
        float4 w2 = wrow[cc * 4 + 2];
        float4 w3 = wrow[cc * 4 + 3];
        acc[0]  += gc * w0.x; acc[1]  += gc * w0.y; acc[2]  += gc * w0.z; acc[3]  += gc * w0.w;
        acc[4]  += gc * w1.x; acc[5]  += gc * w1.y; acc[6]  += gc * w1.z; acc[7]  += gc * w1.w;
        acc[8]  += gc * w2.x; acc[9]  += gc * w2.y; acc[10] += gc * w2.z; acc[11] += gc * w2.w;
        acc[12] += gc * w3.x; acc[13] += gc * w3.y; acc[14] += gc * w3.z; acc[15] += gc * w3.w;
    }
}

// ---------------- K1: coalesced compact (LDS-staged nbr) + conv0 (C=4 -> D=16) ----------------
__global__ __launch_bounds__(256) void k1_compact_conv0(
    const float* __restrict__ feats,  // [N,4]
    const int* __restrict__ nbr,      // [N,27]
    const float* __restrict__ W,      // [27,4,16]
    const float* __restrict__ s, const float* __restrict__ b,
    int* __restrict__ ent,            // [27,N] packed (idx<<5)|k
    int* __restrict__ cnt,            // [N]
    float* __restrict__ x) {          // [N,16]
    __shared__ int   lnbr[256 * 27];  // row stride 27 words: lane reads t*27+k, gcd(27,32)=1 -> conflict-free
    __shared__ float Wl[27 * 68];     // 64-float blocks padded to 68
    int t = threadIdx.x;
    int base = blockIdx.x * 256;
    for (int i = t; i < 27 * 64; i += 256)
        Wl[(i >> 6) * 68 + (i & 63)] = W[i];
    int nv = NVOX - base; if (nv > 256) nv = 256;
    int count = nv * 27;
    const int* gsrc = nbr + base * 27;
    for (int i = t; i < count; i += 256)
        lnbr[i] = gsrc[i];            // fully coalesced global read
    __syncthreads();

    int n = base + t;
    if (n >= NVOX) return;
    int* row = lnbr + t * 27;
    int c = 0;
    #pragma unroll
    for (int k = 0; k < 27; ++k) {
        int idx = row[k];
        if (idx >= 0) {
            int e = (idx << 5) | k;
            row[c] = e;               // in-place compaction: c <= k, never clobbers unread
            ent[c * NVOX + n] = e;
            ++c;
        }
    }
    cnt[n] = c;

    // conv0: uniform loop over compacted entries (from LDS), prefetched feature gathers
    float acc[16];
    #pragma unroll
    for (int d = 0; d < 16; ++d) acc[d] = 0.f;
    int e = row[0];                   // c >= 1 always (center k=13 is self)
    float4 f = *(const float4*)(feats + (e >> 5) * 4);
    int j = 0;
    while (true) {
        bool more = (++j < c);
        int en = e; float4 fn = f;
        if (more) {
            en = row[j];
            fn = *(const float4*)(feats + (en >> 5) * 4);
        }
        {
            const float4* wrow = (const float4*)(Wl + (e & 31) * 68);
            float g[4] = {f.x, f.y, f.z, f.w};
            #pragma unroll
            for (int cc = 0; cc < 4; ++cc) {
                float gc = g[cc];
                float4 w0 = wrow[cc * 4 + 0];
                float4 w1 = wrow[cc * 4 + 1];
                float4 w2 = wrow[cc * 4 + 2];
                float4 w3 = wrow[cc * 4 + 3];
                acc[0]  += gc * w0.x; acc[1]  += gc * w0.y; acc[2]  += gc * w0.z; acc[3]  += gc * w0.w;
                acc[4]  += gc * w1.x; acc[5]  += gc * w1.y; acc[6]  += gc * w1.z; acc[7]  += gc * w1.w;
                acc[8]  += gc * w2.x; acc[9]  += gc * w2.y; acc[10] += gc * w2.z; acc[11] += gc * w2.w;
                acc[12] += gc * w3.x; acc[13] += gc * w3.y; acc[14] += gc * w3.z; acc[15] += gc * w3.w;
            }
        }
        if (!more) break;
        e = en; f = fn;
    }
    float4* o = (float4*)(x + n * 16);
    #pragma unroll
    for (int q = 0; q < 4; ++q) {
        float4 r;
        float v0 = acc[q * 4 + 0] * s[q * 4 + 0] + b[q * 4 + 0];
        float v1 = acc[q * 4 + 1] * s[q * 4 + 1] + b[q * 4 + 1];
        float v2 = acc[q * 4 + 2] * s[q * 4 + 2] + b[q * 4 + 2];
        float v3 = acc[q * 4 + 3] * s[q * 4 + 3] + b[q * 4 + 3];
        r.x = v0 > 0.f ? v0 : 0.f;
        r.y = v1 > 0.f ? v1 : 0.f;
        r.z = v2 > 0.f ? v2 : 0.f;
        r.w = v3 > 0.f ? v3 : 0.f;
        o[q] = r;
    }
}

// ---------------- 16->16 conv core with 1-deep software prefetch ----------------
__device__ __forceinline__ void conv16_core(const float* __restrict__ fin,
                                            const int* __restrict__ ent,
                                            int c, int n, const float* Wl,
                                            float acc[16]) {
    int e = ent[n];                   // j=0 (center) always present
    const float4* fp = (const float4*)(fin + (e >> 5) * 16);
    float4 f0 = fp[0], f1 = fp[1], f2 = fp[2], f3 = fp[3];
    int j = 0;
    while (true) {
        bool more = (++j < c);
        int en = e;
        float4 g0 = f0, g1 = f1, g2 = f2, g3 = f3;
        if (more) {
            en = ent[j * NVOX + n];   // issue next entry + its feature row before computing this one
            const float4* fq = (const float4*)(fin + (en >> 5) * 16);
            g0 = fq[0]; g1 = fq[1]; g2 = fq[2]; g3 = fq[3];
        }
        fma16x16((const float4*)(Wl + (e & 31) * 260), f0, f1, f2, f3, acc);
        if (!more) break;
        e = en; f0 = g0; f1 = g1; f2 = g2; f3 = g3;
    }
}

// ---------------- K2: conv1 (16->16), relu(conv*s+b) ----------------
__global__ __launch_bounds__(256) void k2_conv1(
    const float* __restrict__ fin,    // x [N,16]
    const int* __restrict__ ent, const int* __restrict__ cnt,
    const float* __restrict__ W,      // [27,16,16]
    const float* __restrict__ s, const float* __restrict__ b,
    float* __restrict__ out) {        // h [N,16]
    __shared__ float Wl[27 * 260];
    for (int i = threadIdx.x; i < 27 * 256; i += 256)
        Wl[(i >> 8) * 260 + (i & 255)] = W[i];
    __syncthreads();
    int n = blockIdx.x * 256 + threadIdx.x;
    if (n >= NVOX) return;
    int c = cnt[n];
    float acc[16];
    #pragma unroll
    for (int d = 0; d < 16; ++d) acc[d] = 0.f;
    conv16_core(fin, ent, c, n, Wl, acc);
    float4* o = (float4*)(out + n * 16);
    #pragma unroll
    for (int q = 0; q < 4; ++q) {
        float4 r;
        float v0 = acc[q * 4 + 0] * s[q * 4 + 0] + b[q * 4 + 0];
        float v1 = acc[q * 4 + 1] * s[q * 4 + 1] + b[q * 4 + 1];
        float v2 = acc[q * 4 + 2] * s[q * 4 + 2] + b[q * 4 + 2];
        float v3 = acc[q * 4 + 3] * s[q * 4 + 3] + b[q * 4 + 3];
        r.x = v0 > 0.f ? v0 : 0.f;
        r.y = v1 > 0.f ? v1 : 0.f;
        r.z = v2 > 0.f ? v2 : 0.f;
        r.w = v3 > 0.f ? v3 : 0.f;
        o[q] = r;
    }
}

// ---------------- K3: conv2 + residual + relu + final 16->3 linear ----------------
__global__ __launch_bounds__(256) void k3_conv2_final(
    const float* __restrict__ fin,    // h [N,16]
    const int* __restrict__ ent, const int* __restrict__ cnt,
    const float* __restrict__ W,      // [27,16,16]
    const float* __restrict__ s, const float* __restrict__ b,
    const float* __restrict__ idn,    // x [N,16]
    const float* __restrict__ Wlin,   // [16,3]
    const float* __restrict__ blin,   // [3]
    float* __restrict__ out) {        // [N,3]
    __shared__ float Wl[27 * 260];
    for (int i = threadIdx.x; i < 27 * 256; i += 256)
        Wl[(i >> 8) * 260 + (i & 255)] = W[i];
    __syncthreads();
    int n = blockIdx.x * 256 + threadIdx.x;
    if (n >= NVOX) return;
    int c = cnt[n];
    float acc[16];
    #pragma unroll
    for (int d = 0; d < 16; ++d) acc[d] = 0.f;
    conv16_core(fin, ent, c, n, Wl, acc);
    const float4* ip = (const float4*)(idn + n * 16);
    float4 i0 = ip[0], i1 = ip[1], i2 = ip[2], i3 = ip[3];
    float id[16] = {i0.x, i0.y, i0.z, i0.w, i1.x, i1.y, i1.z, i1.w,
                    i2.x, i2.y, i2.z, i2.w, i3.x, i3.y, i3.z, i3.w};
    float o0 = blin[0], o1 = blin[1], o2 = blin[2];
    #pragma unroll
    for (int d = 0; d < 16; ++d) {
        float v = acc[d] * s[d] + b[d] + id[d];
        v = v > 0.f ? v : 0.f;
        o0 += v * Wlin[d * 3 + 0];
        o1 += v * Wlin[d * 3 + 1];
        o2 += v * Wlin[d * 3 + 2];
    }
    out[n * 3 + 0] = o0;
    out[n * 3 + 1] = o1;
    out[n * 3 + 2] = o2;
}

extern "C" void kernel_launch(void* const* d_in, const int* in_sizes, int n_in,
                              void* d_out, int out_size, void* d_ws, size_t ws_size,
                              hipStream_t stream) {
    const float* feats = (const float*)d_in[0];
    const int*   nbr   = (const int*)d_in[1];
    const float* W0    = (const float*)d_in[2];
    const float* s0    = (const float*)d_in[3];
    const float* b0    = (const float*)d_in[4];
    const float* W1    = (const float*)d_in[5];
    const float* s1    = (const float*)d_in[6];
    const float* b1    = (const float*)d_in[7];
    const float* W2    = (const float*)d_in[8];
    const float* s2    = (const float*)d_in[9];
    const float* b2    = (const float*)d_in[10];
    const float* Wlin  = (const float*)d_in[11];
    const float* blin  = (const float*)d_in[12];
    float* out = (float*)d_out;

    char* ws = (char*)d_ws;
    int*   ent = (int*)(ws);               // 27*N*4 = 21,600,000
    int*   cnt = (int*)(ws + 21600000);    // 800,000
    float* x   = (float*)(ws + 22400000);  // 12,800,000
    float* h   = (float*)(ws + 35200000);  // 12,800,000

    int blocks = (NVOX + 255) / 256;
    k1_compact_conv0<<<blocks, 256, 0, stream>>>(feats, nbr, W0, s0, b0, ent, cnt, x);
    k2_conv1<<<blocks, 256, 0, stream>>>(x, ent, cnt, W1, s1, b1, h);
    k3_conv2_final<<<blocks, 256, 0, stream>>>(h, ent, cnt, W2, s2, b2, x, Wlin, blin, out);
}